// Round 2
// baseline (92.720 us; speedup 1.0000x reference)
//
#include <hip/hip_runtime.h>
#include <hip/hip_bf16.h>

#define B_DIM 16384
#define P_DIM 4096
#define D_DIM 256
#define BK 64
#define NT (D_DIM / BK)  // 4

typedef float f32x4 __attribute__((ext_vector_type(4)));
typedef __bf16 bf16x8 __attribute__((ext_vector_type(8)));

__device__ __forceinline__ unsigned short f2bf_rne(float f) {
  unsigned int u = __builtin_bit_cast(unsigned int, f);
  u += 0x7fffu + ((u >> 16) & 1u);
  return (unsigned short)(u >> 16);
}

// One wave per row: fp32 -> bf16 conversion + fp32 sum-of-squares.
__global__ __launch_bounds__(256) void prep_kernel(
    const float* __restrict__ x, const float* __restrict__ p,
    unsigned short* __restrict__ xb, unsigned short* __restrict__ pb,
    float* __restrict__ xsq, float* __restrict__ psq) {
  int row  = blockIdx.x * 4 + (threadIdx.x >> 6);
  int lane = threadIdx.x & 63;
  const float4* src;
  unsigned short* dst;
  float* sq;
  if (row < B_DIM) {
    src = (const float4*)(x + (size_t)row * D_DIM);
    dst = xb + (size_t)row * D_DIM;
    sq  = xsq + row;
  } else {
    int r = row - B_DIM;
    src = (const float4*)(p + (size_t)r * D_DIM);
    dst = pb + (size_t)r * D_DIM;
    sq  = psq + r;
  }
  float4 v = src[lane];
  ushort4 o;
  o.x = f2bf_rne(v.x); o.y = f2bf_rne(v.y);
  o.z = f2bf_rne(v.z); o.w = f2bf_rne(v.w);
  ((ushort4*)dst)[lane] = o;
  float s = v.x * v.x + v.y * v.y + v.z * v.z + v.w * v.w;
  #pragma unroll
  for (int off = 32; off > 0; off >>= 1) s += __shfl_down(s, off);
  if (lane == 0) *sq = s;
}

__device__ __forceinline__ void async16(const unsigned short* g, void* l) {
  __builtin_amdgcn_global_load_lds(
      (const __attribute__((address_space(1))) void*)g,
      (__attribute__((address_space(3))) void*)l,
      16, 0, 0);
}

// 128x128 tile, BK=64, dbuf LDS with XOR swizzle, T3-min 2-phase pipeline.
__global__ __launch_bounds__(256, 2) void dist_gemm(
    const unsigned short* __restrict__ A,   // [B_DIM][D_DIM] bf16 bits
    const unsigned short* __restrict__ Bm,  // [P_DIM][D_DIM] bf16 bits
    const float* __restrict__ xsq, const float* __restrict__ psq,
    float* __restrict__ out) {
  // [buf][A|B][128 rows x 64 cols bf16] = 2*2*16 KB = 64 KB
  __shared__ __align__(16) char lds[2][2][128 * BK * 2];

  const int tid  = threadIdx.x;
  const int w    = tid >> 6;
  const int lane = tid & 63;

  // XCD-aware bijective swizzle (4096 blocks, 8 XCDs, 4096%8==0)
  const int bid = blockIdx.x;
  const int swz = (bid & 7) * 512 + (bid >> 3);
  const int bm  = swz >> 5;  // 0..127
  const int bn  = swz & 31;  // 0..31

  const int wr = w >> 1;
  const int wc = w & 1;

  f32x4 acc[4][4];
  #pragma unroll
  for (int m = 0; m < 4; ++m)
    #pragma unroll
    for (int n = 0; n < 4; ++n) acc[m][n] = 0.0f;

  // Staging: 16 KB per matrix tile; wave w covers bytes [w*4096, w*4096+4096)
  // in 4 x 1024 B global_load_lds (16 B/lane, linear LDS dest).
  // Read side XOR-swizzles byte ^= (row&7)<<4, so the per-lane GLOBAL source
  // is pre-swizzled with the same involution (rule 21: both-sides-or-neither).
  const unsigned short* asrc[4];
  const unsigned short* bsrc[4];
  int lofs[4];
  #pragma unroll
  for (int l = 0; l < 4; ++l) {
    int q  = w * 4096 + l * 1024 + lane * 16;  // physical byte in 16 KB tile
    int r  = q >> 7;                           // row (128 B rows)
    int cb = (q & 127) ^ ((r & 7) << 4);       // logical col byte (involution)
    asrc[l] = A  + (size_t)(bm * 128 + r) * D_DIM + (cb >> 1);
    bsrc[l] = Bm + (size_t)(bn * 128 + r) * D_DIM + (cb >> 1);
    lofs[l] = w * 4096 + l * 1024;
  }

#define STAGE(buf, kt) do {                                      \
    _Pragma("unroll")                                            \
    for (int l = 0; l < 4; ++l) {                                \
      async16(asrc[l] + (kt), (void*)(lds[buf][0] + lofs[l]));   \
      async16(bsrc[l] + (kt), (void*)(lds[buf][1] + lofs[l]));   \
    } } while (0)

  const int ar   = wr * 64 + (lane & 15);
  const int br   = wc * 64 + (lane & 15);
  const int xr   = (lane & 7) << 4;       // row&7 == lane&7 for all fragments
  const int kcol = (lane >> 4) * 16;      // byte col of this lane's k-chunk

  // Prologue: stage tile 0, wait, barrier.
  STAGE(0, 0);
  asm volatile("s_waitcnt vmcnt(0)" ::: "memory");
  __builtin_amdgcn_s_barrier();
  __builtin_amdgcn_sched_barrier(0);

  #pragma unroll
  for (int t = 0; t < NT; ++t) {
    if (t < NT - 1) STAGE((t + 1) & 1, (t + 1) * BK);  // prefetch next K-tile

    const char* La = lds[t & 1][0];
    const char* Lb = lds[t & 1][1];
    #pragma unroll
    for (int qk = 0; qk < 2; ++qk) {
      bf16x8 av[4], bv[4];
      #pragma unroll
      for (int m = 0; m < 4; ++m) {
        int row = ar + m * 16;
        av[m] = *(const bf16x8*)(La + row * 128 + ((kcol + qk * 64) ^ xr));
      }
      #pragma unroll
      for (int n = 0; n < 4; ++n) {
        int row = br + n * 16;
        bv[n] = *(const bf16x8*)(Lb + row * 128 + ((kcol + qk * 64) ^ xr));
      }
      #pragma unroll
      for (int m = 0; m < 4; ++m)
        #pragma unroll
        for (int n = 0; n < 4; ++n)
          acc[m][n] = __builtin_amdgcn_mfma_f32_16x16x32_bf16(av[m], bv[n], acc[m][n], 0, 0, 0);
    }

    if (t < NT - 1) {
      // Drain this iter's prefetch loads + barrier: next iter reads them.
      asm volatile("s_waitcnt vmcnt(0)" ::: "memory");
      __builtin_amdgcn_s_barrier();
      __builtin_amdgcn_sched_barrier(0);
    }
  }

  // Epilogue: out = sqrt(max(xsq + psq - 2*xp, 0))
  // C/D layout (verified): col = lane&15, row = (lane>>4)*4 + reg
  const int row0 = bm * 128 + wr * 64 + (lane >> 4) * 4;
  const int col0 = bn * 128 + wc * 64 + (lane & 15);
  #pragma unroll
  for (int m = 0; m < 4; ++m) {
    #pragma unroll
    for (int n = 0; n < 4; ++n) {
      const int col = col0 + n * 16;
      const float ps = psq[col];
      #pragma unroll
      for (int j = 0; j < 4; ++j) {
        const int row = row0 + m * 16 + j;
        const float xs = xsq[row];
        float v = fmaf(-2.0f, acc[m][n][j], xs + ps);
        v = fmaxf(v, 0.0f);
        __builtin_nontemporal_store(__builtin_sqrtf(v),
                                    &out[(size_t)row * P_DIM + col]);
      }
    }
  }
#undef STAGE
}

extern "C" void kernel_launch(void* const* d_in, const int* in_sizes, int n_in,
                              void* d_out, int out_size, void* d_ws, size_t ws_size,
                              hipStream_t stream) {
  const float* x = (const float*)d_in[0];
  const float* p = (const float*)d_in[1];
  float* out = (float*)d_out;

  char* ws = (char*)d_ws;
  unsigned short* xb = (unsigned short*)ws;                                // 8 MB
  unsigned short* pb = (unsigned short*)(ws + (size_t)B_DIM * D_DIM * 2);  // 2 MB
  float* xsq = (float*)(ws + (size_t)(B_DIM + P_DIM) * D_DIM * 2);
  float* psq = xsq + B_DIM;

  prep_kernel<<<(B_DIM + P_DIM) / 4, 256, 0, stream>>>(x, p, xb, pb, xsq, psq);

  dist_gemm<<<(B_DIM / 128) * (P_DIM / 128), 256, 0, stream>>>(xb, pb, xsq, psq, out);
}